// Round 7
// baseline (1040.194 us; speedup 1.0000x reference)
//
#include <hip/hip_runtime.h>
#include <hip/hip_bf16.h>

#define NB 4
#define CCH 256
#define CRD 32
#define NN 4096

typedef __attribute__((ext_vector_type(8))) short short8;
typedef __attribute__((ext_vector_type(4))) float floatx4;
typedef __attribute__((ext_vector_type(4))) int intx4;
typedef __attribute__((ext_vector_type(2))) unsigned int uintx2;

__device__ __forceinline__ unsigned short f2bf(float f) {
  unsigned u = __builtin_bit_cast(unsigned, f);
  u += 0x7FFFu + ((u >> 16) & 1u);
  return (unsigned short)(u >> 16);
}

// Clamped convert: finite bf16 regardless of input (NaN -> -1e4 via IEEE
// maxNum/minNum, +-inf -> +-1e4). Legit qkv values |v| < ~20: transparent.
__device__ __forceinline__ unsigned short f2bf_c(float f) {
  f = fminf(fmaxf(f, -1.0e4f), 1.0e4f);
  unsigned u = __builtin_bit_cast(unsigned, f);
  u += 0x7FFFu + ((u >> 16) & 1u);
  return (unsigned short)(u >> 16);
}

__device__ __forceinline__ unsigned pack2c(float a, float b) {
  return (unsigned)f2bf_c(a) | ((unsigned)f2bf_c(b) << 16);
}

// Output sanitizer: NaN -> -1e30 (IEEE maxNum), +-inf -> +-1e30.
__device__ __forceinline__ float sat(float v) {
  return fminf(fmaxf(v, -1.0e30f), 1.0e30f);
}

__device__ __forceinline__ short8 ld_frag_g(const unsigned short* p) {
  return __builtin_bit_cast(short8, *(const intx4*)p);
}

// 16B global -> LDS. DMA path: LDS dest is wave-uniform base + lane*16
// (hardware-implicit); global src is per-lane. Fallback replicates exactly.
#if __has_builtin(__builtin_amdgcn_global_load_lds)
#define HAS_GLDS 1
#endif
__device__ __forceinline__ void gl_lds16(const unsigned short* g,
                                         unsigned char* lbase, int lane) {
#ifdef HAS_GLDS
  (void)lane;
  __builtin_amdgcn_global_load_lds(
      (const __attribute__((address_space(1))) unsigned int*)g,
      (__attribute__((address_space(3))) unsigned int*)lbase, 16, 0, 0);
#else
  *(intx4*)(lbase + lane * 16) = *(const intx4*)g;
#endif
}

// ---------------------------------------------------------------------------
// Kernel 1: fused transpose + QKV GEMM (unchanged; stable since round 2).
// ---------------------------------------------------------------------------
__global__ __launch_bounds__(256) void gemm_qkv_fused(
    const float* __restrict__ x,
    const float* __restrict__ Wq, const float* __restrict__ bq,
    const float* __restrict__ Wk, const float* __restrict__ bk,
    const float* __restrict__ Wv, const float* __restrict__ bv,
    unsigned short* __restrict__ qT, unsigned short* __restrict__ kT,
    unsigned short* __restrict__ vv)
{
  __shared__ __align__(16) unsigned short xs[64 * 264];
  __shared__ __align__(16) unsigned short ws[64 * 264];

  const int tid  = threadIdx.x;
  const int wave = tid >> 6;
  const int lane = tid & 63;
  const int lq   = lane >> 4;
  const int lm   = lane & 15;
  const int n0   = blockIdx.x << 6;
  const int mg   = blockIdx.y;
  const int b    = blockIdx.z;

  {
    const int nn = lane;
    const int cg = wave;
    const float* xb = x + ((size_t)b << 20) + n0 + nn;
#pragma unroll
    for (int it = 0; it < 16; ++it) {
      const int c0 = it * 16 + cg * 4;
      const float v0 = xb[(size_t)(c0 + 0) << 12];
      const float v1 = xb[(size_t)(c0 + 1) << 12];
      const float v2 = xb[(size_t)(c0 + 2) << 12];
      const float v3 = xb[(size_t)(c0 + 3) << 12];
      uintx2 u;
      u[0] = pack2c(v0, v1);
      u[1] = pack2c(v2, v3);
      *(uintx2*)(xs + nn * 264 + c0) = u;
    }
  }

  const int mt_lo = mg ? 3 : 0;
  const int mt_hi = mg ? 5 : 3;

  for (int mt = mt_lo; mt < mt_hi; ++mt) {
#pragma unroll
    for (int i = 0; i < 16; ++i) {
      const int u  = i * 256 + tid;
      const int m  = u >> 6;
      const int o4 = (u & 63) * 4;
      const float* src = (mt == 0)
          ? (m < 32 ? Wq + (size_t)m * CCH : Wk + (size_t)(m - 32) * CCH)
          : Wv + (size_t)((mt - 1) * 64 + m) * CCH;
      const floatx4 f = *(const floatx4*)(src + o4);
      uintx2 uu;
      uu[0] = pack2c(f[0], f[1]);
      uu[1] = pack2c(f[2], f[3]);
      *(uintx2*)(ws + m * 264 + o4) = uu;
    }
    __syncthreads();

    floatx4 acc[4];
#pragma unroll
    for (int t = 0; t < 4; ++t) acc[t] = (floatx4){0.f, 0.f, 0.f, 0.f};

#pragma unroll
    for (int k0 = 0; k0 < 8; ++k0) {
      short8 af[4];
#pragma unroll
      for (int ms = 0; ms < 4; ++ms)
        af[ms] = __builtin_bit_cast(short8,
            *(const intx4*)(ws + (ms * 16 + lm) * 264 + k0 * 32 + lq * 8));
      const short8 bf = __builtin_bit_cast(short8,
          *(const intx4*)(xs + (wave * 16 + lm) * 264 + k0 * 32 + lq * 8));
#pragma unroll
      for (int ms = 0; ms < 4; ++ms)
        acc[ms] = __builtin_amdgcn_mfma_f32_16x16x32_bf16(af[ms], bf,
                                                          acc[ms], 0, 0, 0);
    }
    __syncthreads();

    if (mt == 0) {
      const int n = n0 + wave * 16 + lm;
#pragma unroll
      for (int ms = 0; ms < 4; ++ms) {
        const int d0 = (ms & 1) * 16 + lq * 4;
        const float* bias = (ms < 2) ? bq : bk;
        unsigned short* dst = (ms < 2) ? qT : kT;
        uintx2 u;
        u[0] = pack2c(acc[ms][0] + bias[d0],     acc[ms][1] + bias[d0 + 1]);
        u[1] = pack2c(acc[ms][2] + bias[d0 + 2], acc[ms][3] + bias[d0 + 3]);
        *(uintx2*)(dst + (size_t)(b * NN + n) * CRD + d0) = u;
      }
    } else {
      const int cb = (mt - 1) * 64;
      unsigned short* vb2 = ws;
#pragma unroll
      for (int ms = 0; ms < 4; ++ms)
#pragma unroll
        for (int r = 0; r < 4; ++r) {
          const int c = ms * 16 + lq * 4 + r;
          vb2[c * 64 + wave * 16 + lm] = f2bf_c(acc[ms][r] + bv[cb + c]);
        }
      __syncthreads();
#pragma unroll
      for (int it = 0; it < 2; ++it) {
        const int u = it * 256 + tid;
        const int m = u >> 3;
        const int o = (u & 7) * 8;
        *(intx4*)(vv + (size_t)(b * CCH + cb + m) * NN + n0 + o) =
            *(const intx4*)(vb2 + m * 64 + o);
      }
      __syncthreads();
    }
  }
}

// ---------------------------------------------------------------------------
// Kernel 2: attention, round-18 = the round-1 best (80.2 us, 4wg x 2cs,
// P double-buffered via LDS, one barrier/iter -- layout math verbatim) with
// two targeted deltas:
//  (a) V staging via global_load_lds DMA: LDS dest linear (wave base +
//      lane*16), global src granule pre-swizzled ((lane&7)^(lane>>3)) so the
//      LDS image is bit-identical to round-1's swizzled layout (rule #21:
//      swizzle both sides or neither). Kills 4 loads + 8 ds_writes + 16 live
//      VGPRs per thread per iter.
//  (b) iteration reordered to [barrier] -> DMA(k+1) -> PV(k) || QK(k+1)+exp+
//      P-store(k+1): PV(k) and QK(k+1) are data-independent, so exp VALU
//      hides under PV MFMAs instead of serializing ahead of them.
// ---------------------------------------------------------------------------
__global__ __launch_bounds__(512) void attn_kernel(
    const float* __restrict__ x, const float* __restrict__ gamma_p,
    const unsigned short* __restrict__ qT, const unsigned short* __restrict__ kT,
    const unsigned short* __restrict__ vv, float* __restrict__ out)
{
  // [0,65536): V double buffer (2 x 256c x 64j bf16, swizzled granules)
  // [65536, +17408): P double buffer (2 parity x 4 wg x 16 i x 68col shorts)
  __shared__ __align__(16) unsigned char smem[65536 + 2 * 4 * 2176];

  const int tid  = threadIdx.x;
  const int wave = tid >> 6;
  const int wg   = wave >> 1;   // row-group 0..3 (16 rows each)
  const int cs   = wave & 1;    // c-slice / jt-half 0..1
  const int lane = tid & 63;
  const int lq   = lane >> 4;
  const int lm   = lane & 15;
  const int xcd = blockIdx.x & 7;
  const int pos = blockIdx.x >> 3;
  const int b   = xcd >> 1;
  const int i0  = (((xcd & 1) << 5) | pos) << 6;

  const unsigned short* kTb = kT + (size_t)b * NN * CRD;
  const unsigned short* vb  = vv + (size_t)b * CCH * NN;

  const short8 qf =
      ld_frag_g(qT + (size_t)(b * NN + i0 + wg * 16 + lm) * CRD + lq * 8);

  // V DMA coords: wave covers rows cm..cm+7 per chunk m (cm = m*64+wave*8,
  // multiple of 8). Lane l -> row cm+(l>>3), LDS granule l&7 (linear dest).
  // Required global granule = (l&7) ^ (row&7) = (l&7) ^ (l>>3).
  const int l8 = lane >> 3, g8 = lane & 7;
  size_t vsrc[4];
  int    vdst[4];
#pragma unroll
  for (int m = 0; m < 4; ++m) {
    const int cm = m * 64 + wave * 8;
    vsrc[m] = (size_t)(cm + l8) * NN + ((g8 ^ l8) << 3);
    vdst[m] = cm * 128;
  }

  floatx4 acc[8];
#pragma unroll
  for (int t = 0; t < 8; ++t) acc[t] = (floatx4){0.f, 0.f, 0.f, 0.f};
  float lsum[4] = {0.f, 0.f, 0.f, 0.f};

  const floatx4 zf = {0.f, 0.f, 0.f, 0.f};

  // K frag double buffer: kf[p] = window with parity p to be consumed next
  short8 kf[2][2];
#pragma unroll
  for (int jt = 0; jt < 2; ++jt) {
    kf[0][jt] =
        ld_frag_g(kTb + (size_t)((cs * 2 + jt) * 16 + lm) * CRD + lq * 8);
    kf[1][jt] =
        ld_frag_g(kTb + (size_t)(64 + (cs * 2 + jt) * 16 + lm) * CRD + lq * 8);
  }

  // prologue: DMA window 0 -> V parity 0; compute + store P(0) -> parity 0
#pragma unroll
  for (int m = 0; m < 4; ++m)
    gl_lds16(vb + vsrc[m], smem + vdst[m], lane);
  {
    unsigned char* pb0 = smem + 65536 + wg * 2176;
#pragma unroll
    for (int jt = 0; jt < 2; ++jt) {
      const floatx4 S = __builtin_amdgcn_mfma_f32_16x16x32_bf16(
          qf, kf[0][jt], zf, 0, 0, 0);
#pragma unroll
      for (int r = 0; r < 4; ++r) {
        const float pv = __expf(fminf(fmaxf(S[r], -40.f), 40.f));
        lsum[r] += pv;
        *(unsigned short*)(pb0 + (lq * 4 + r) * 136 +
                           (((cs * 2 + jt) * 16 + lm) << 1)) = f2bf(pv);
      }
    }
  }

#pragma unroll 1
  for (int k = 0; k < 64; ++k) {
    // A(k): DMA(k) + P(k) visible (pre-barrier waitcnt drains vm+lgkm);
    // PV(k-1) reads of parity (k+1)&1 complete -> safe to overwrite it.
    __syncthreads();
    unsigned char* vbp = smem + ((k & 1) << 15);
    unsigned char* pbp = smem + 65536 + (k & 1) * 8704 + wg * 2176;

    if (k < 63) {
      const size_t j1 = (size_t)((k + 1) << 6);
      unsigned char* vbn = smem + (((k + 1) & 1) << 15);
#pragma unroll
      for (int m = 0; m < 4; ++m)
        gl_lds16(vb + vsrc[m] + j1, vbn + vdst[m], lane);
    }

    // PV(k): this wave's 128-col c-half; reads V/P parity k&1
    __builtin_amdgcn_s_setprio(1);
#pragma unroll
    for (int ks = 0; ks < 2; ++ks) {
      const unsigned char* pa = pbp + lm * 136 + ks * 64 + lq * 16;
      struct U128 { unsigned long long a, b; } pp;
      pp.a = *(const unsigned long long*)pa;
      pp.b = *(const unsigned long long*)(pa + 8);
      const short8 pf = __builtin_bit_cast(short8, pp);
#pragma unroll
      for (int nt = 0; nt < 8; ++nt) {
        const int c = cs * 128 + nt * 16 + lm;
        const short8 vf = __builtin_bit_cast(
            short8,
            *(const intx4*)(vbp + c * 128 + (((ks * 4 + lq) ^ (lm & 7)) * 16)));
        acc[nt] = __builtin_amdgcn_mfma_f32_16x16x32_bf16(pf, vf, acc[nt],
                                                          0, 0, 0);
      }
    }
    __builtin_amdgcn_s_setprio(0);

    // QK(k+1) + exp + P-store(k+1) -> parity (k+1)&1 (independent of PV(k))
    if (k < 63) {
      unsigned char* pbn = smem + 65536 + ((k + 1) & 1) * 8704 + wg * 2176;
#pragma unroll
      for (int jt = 0; jt < 2; ++jt) {
        const floatx4 S = __builtin_amdgcn_mfma_f32_16x16x32_bf16(
            qf, kf[(k + 1) & 1][jt], zf, 0, 0, 0);
#pragma unroll
        for (int r = 0; r < 4; ++r) {
          const float pv = __expf(fminf(fmaxf(S[r], -40.f), 40.f));
          lsum[r] += pv;
          *(unsigned short*)(pbn + (lq * 4 + r) * 136 +
                             (((cs * 2 + jt) * 16 + lm) << 1)) = f2bf(pv);
        }
      }
    }
    // refill kf[k&1] <- window k+2 (same parity)
    if (k < 62) {
      const int j2 = (k + 2) << 6;
#pragma unroll
      for (int jt = 0; jt < 2; ++jt)
        kf[k & 1][jt] = ld_frag_g(
            kTb + (size_t)(j2 + (cs * 2 + jt) * 16 + lm) * CRD + lq * 8);
    }
  }

  // reduce l across the 16 lm lanes (lq groups independent)
  float lred[4];
#pragma unroll
  for (int r = 0; r < 4; ++r) {
    float v = lsum[r];
    v += __shfl_xor(v, 1);
    v += __shfl_xor(v, 2);
    v += __shfl_xor(v, 4);
    v += __shfl_xor(v, 8);
    lred[r] = v;
  }

  // combine partial lsum across the cs wave pair (each saw half the j's)
  __syncthreads();  // all PV(63) reads done; parity-0 V region reusable
  floatx4 lv;
#pragma unroll
  for (int r = 0; r < 4; ++r) lv[r] = lred[r];
  *(floatx4*)(smem + ((wave * 64 + lane) << 4)) = lv;
  __syncthreads();
  const floatx4 lpart = *(const floatx4*)(smem + (((wave ^ 1) * 64 + lane) << 4));

  float inv[4];
#pragma unroll
  for (int r = 0; r < 4; ++r) inv[r] = 1.0f / (lred[r] + lpart[r]);

  const float gm = gamma_p[0];
#pragma unroll
  for (int nt = 0; nt < 8; ++nt) {
#pragma unroll
    for (int r = 0; r < 4; ++r) {
      const int c = cs * 128 + nt * 16 + lm;
      const int i = i0 + wg * 16 + lq * 4 + r;
      const size_t idx = (size_t)(b * CCH + c) * NN + i;
      out[idx] = gm * sat(acc[nt][r] * inv[r]) + x[idx];
    }
  }
}

extern "C" void kernel_launch(void* const* d_in, const int* in_sizes, int n_in,
                              void* d_out, int out_size, void* d_ws, size_t ws_size,
                              hipStream_t stream) {
  (void)in_sizes; (void)n_in; (void)out_size; (void)ws_size;
  const float* x     = (const float*)d_in[0];
  const float* Wq    = (const float*)d_in[1];
  const float* bq    = (const float*)d_in[2];
  const float* Wk    = (const float*)d_in[3];
  const float* bk    = (const float*)d_in[4];
  const float* Wv    = (const float*)d_in[5];
  const float* bv    = (const float*)d_in[6];
  const float* gamma = (const float*)d_in[7];

  unsigned short* qT = (unsigned short*)d_ws;              // 1 MiB
  unsigned short* kT = qT + (size_t)NB * NN * CRD;         // 1 MiB
  unsigned short* vv = kT + (size_t)NB * NN * CRD;         // 8 MiB

  gemm_qkv_fused<<<dim3(64, 2, 4), 256, 0, stream>>>(x, Wq, bq, Wk, bk, Wv, bv,
                                                     qT, kT, vv);
  attn_kernel<<<dim3(256, 1, 1), 512, 0, stream>>>(x, gamma, qT, kT, vv,
                                                   (float*)d_out);
}

// Round 8
// 166.261 us; speedup vs baseline: 6.2564x; 6.2564x over previous
//
#include <hip/hip_runtime.h>
#include <hip/hip_bf16.h>

#define NB 4
#define CCH 256
#define CRD 32
#define NN 4096

typedef __attribute__((ext_vector_type(8))) short short8;
typedef __attribute__((ext_vector_type(4))) float floatx4;
typedef __attribute__((ext_vector_type(4))) int intx4;
typedef __attribute__((ext_vector_type(2))) unsigned int uintx2;

__device__ __forceinline__ unsigned short f2bf(float f) {
  unsigned u = __builtin_bit_cast(unsigned, f);
  u += 0x7FFFu + ((u >> 16) & 1u);
  return (unsigned short)(u >> 16);
}

// Clamped convert: finite bf16 regardless of input (NaN -> -1e4 via IEEE
// maxNum/minNum, +-inf -> +-1e4). Legit qkv values |v| < ~20: transparent.
__device__ __forceinline__ unsigned short f2bf_c(float f) {
  f = fminf(fmaxf(f, -1.0e4f), 1.0e4f);
  unsigned u = __builtin_bit_cast(unsigned, f);
  u += 0x7FFFu + ((u >> 16) & 1u);
  return (unsigned short)(u >> 16);
}

__device__ __forceinline__ unsigned pack2c(float a, float b) {
  return (unsigned)f2bf_c(a) | ((unsigned)f2bf_c(b) << 16);
}

// Output sanitizer: NaN -> -1e30 (IEEE maxNum), +-inf -> +-1e30.
__device__ __forceinline__ float sat(float v) {
  return fminf(fmaxf(v, -1.0e30f), 1.0e30f);
}

__device__ __forceinline__ short8 ld_frag_g(const unsigned short* p) {
  return __builtin_bit_cast(short8, *(const intx4*)p);
}

// ---------------------------------------------------------------------------
// Kernel 1: fused transpose + QKV GEMM (unchanged; stable since round 3).
// ---------------------------------------------------------------------------
__global__ __launch_bounds__(256) void gemm_qkv_fused(
    const float* __restrict__ x,
    const float* __restrict__ Wq, const float* __restrict__ bq,
    const float* __restrict__ Wk, const float* __restrict__ bk,
    const float* __restrict__ Wv, const float* __restrict__ bv,
    unsigned short* __restrict__ qT, unsigned short* __restrict__ kT,
    unsigned short* __restrict__ vv)
{
  __shared__ __align__(16) unsigned short xs[64 * 264];
  __shared__ __align__(16) unsigned short ws[64 * 264];

  const int tid  = threadIdx.x;
  const int wave = tid >> 6;
  const int lane = tid & 63;
  const int lq   = lane >> 4;
  const int lm   = lane & 15;
  const int n0   = blockIdx.x << 6;
  const int mg   = blockIdx.y;
  const int b    = blockIdx.z;

  {
    const int nn = lane;
    const int cg = wave;
    const float* xb = x + ((size_t)b << 20) + n0 + nn;
#pragma unroll
    for (int it = 0; it < 16; ++it) {
      const int c0 = it * 16 + cg * 4;
      const float v0 = xb[(size_t)(c0 + 0) << 12];
      const float v1 = xb[(size_t)(c0 + 1) << 12];
      const float v2 = xb[(size_t)(c0 + 2) << 12];
      const float v3 = xb[(size_t)(c0 + 3) << 12];
      uintx2 u;
      u[0] = pack2c(v0, v1);
      u[1] = pack2c(v2, v3);
      *(uintx2*)(xs + nn * 264 + c0) = u;
    }
  }

  const int mt_lo = mg ? 3 : 0;
  const int mt_hi = mg ? 5 : 3;

  for (int mt = mt_lo; mt < mt_hi; ++mt) {
#pragma unroll
    for (int i = 0; i < 16; ++i) {
      const int u  = i * 256 + tid;
      const int m  = u >> 6;
      const int o4 = (u & 63) * 4;
      const float* src = (mt == 0)
          ? (m < 32 ? Wq + (size_t)m * CCH : Wk + (size_t)(m - 32) * CCH)
          : Wv + (size_t)((mt - 1) * 64 + m) * CCH;
      const floatx4 f = *(const floatx4*)(src + o4);
      uintx2 uu;
      uu[0] = pack2c(f[0], f[1]);
      uu[1] = pack2c(f[2], f[3]);
      *(uintx2*)(ws + m * 264 + o4) = uu;
    }
    __syncthreads();

    floatx4 acc[4];
#pragma unroll
    for (int t = 0; t < 4; ++t) acc[t] = (floatx4){0.f, 0.f, 0.f, 0.f};

#pragma unroll
    for (int k0 = 0; k0 < 8; ++k0) {
      short8 af[4];
#pragma unroll
      for (int ms = 0; ms < 4; ++ms)
        af[ms] = __builtin_bit_cast(short8,
            *(const intx4*)(ws + (ms * 16 + lm) * 264 + k0 * 32 + lq * 8));
      const short8 bf = __builtin_bit_cast(short8,
          *(const intx4*)(xs + (wave * 16 + lm) * 264 + k0 * 32 + lq * 8));
#pragma unroll
      for (int ms = 0; ms < 4; ++ms)
        acc[ms] = __builtin_amdgcn_mfma_f32_16x16x32_bf16(af[ms], bf,
                                                          acc[ms], 0, 0, 0);
    }
    __syncthreads();

    if (mt == 0) {
      const int n = n0 + wave * 16 + lm;
#pragma unroll
      for (int ms = 0; ms < 4; ++ms) {
        const int d0 = (ms & 1) * 16 + lq * 4;
        const float* bias = (ms < 2) ? bq : bk;
        unsigned short* dst = (ms < 2) ? qT : kT;
        uintx2 u;
        u[0] = pack2c(acc[ms][0] + bias[d0],     acc[ms][1] + bias[d0 + 1]);
        u[1] = pack2c(acc[ms][2] + bias[d0 + 2], acc[ms][3] + bias[d0 + 3]);
        *(uintx2*)(dst + (size_t)(b * NN + n) * CRD + d0) = u;
      }
    } else {
      const int cb = (mt - 1) * 64;
      unsigned short* vb2 = ws;
#pragma unroll
      for (int ms = 0; ms < 4; ++ms)
#pragma unroll
        for (int r = 0; r < 4; ++r) {
          const int c = ms * 16 + lq * 4 + r;
          vb2[c * 64 + wave * 16 + lm] = f2bf_c(acc[ms][r] + bv[cb + c]);
        }
      __syncthreads();
#pragma unroll
      for (int it = 0; it < 2; ++it) {
        const int u = it * 256 + tid;
        const int m = u >> 3;
        const int o = (u & 7) * 8;
        *(intx4*)(vv + (size_t)(b * CCH + cb + m) * NN + n0 + o) =
            *(const intx4*)(vb2 + m * 64 + o);
      }
      __syncthreads();
    }
  }
}

// ---------------------------------------------------------------------------
// Kernel 2: attention = the measured-best 80.16 us kernel (4wg x 2cs, QK
// split across the cs pair, V+P double-buffered, ONE barrier/iter), layout
// math VERBATIM, with exactly one delta:
//   T4 counted-drain barrier: __syncthreads() (which emits s_waitcnt
//   vmcnt(0) lgkmcnt(0) + s_barrier) is replaced by
//       asm("s_waitcnt lgkmcnt(0)") + __builtin_amdgcn_s_barrier().
//   Correctness needs only the LDS drain (P-store + V-stage ds_writes
//   visible across waves). The vmcnt(0) drain was forcing every wave to eat
//   the L2/HBM tail of its own private vreg/kf register prefetches at every
//   one of the 64 barriers; those are consumed later with compiler-inserted
//   fine-grained vmcnt waits and may legally stay in flight across the
//   barrier (AITER/HK never-drain pattern).
// ---------------------------------------------------------------------------
__global__ __launch_bounds__(512) void attn_kernel(
    const float* __restrict__ x, const float* __restrict__ gamma_p,
    const unsigned short* __restrict__ qT, const unsigned short* __restrict__ kT,
    const unsigned short* __restrict__ vv, float* __restrict__ out)
{
  // [0,65536): V double buffer (2 x 256c x 64j bf16, swizzled)
  // [65536, +17408): P double buffer (2 parity x 4 wg x 16 i x 68col shorts)
  __shared__ __align__(16) unsigned char smem[65536 + 2 * 4 * 2176];

  const int tid  = threadIdx.x;
  const int wave = tid >> 6;
  const int wg   = wave >> 1;   // row-group 0..3 (16 rows each)
  const int cs   = wave & 1;    // c-slice / jt-half 0..1
  const int lane = tid & 63;
  const int lq   = lane >> 4;
  const int lm   = lane & 15;
  const int xcd = blockIdx.x & 7;
  const int pos = blockIdx.x >> 3;
  const int b   = xcd >> 1;
  const int i0  = (((xcd & 1) << 5) | pos) << 6;

  const unsigned short* kTb = kT + (size_t)b * NN * CRD;
  const unsigned short* vb  = vv + (size_t)b * CCH * NN;

  const short8 qf =
      ld_frag_g(qT + (size_t)(b * NN + i0 + wg * 16 + lm) * CRD + lq * 8);

  // per-lane V-stage coordinates: unit u = m*512+tid; c = u>>3; jb = u&7
  int vs_g[4];
  int vs_off[4];
#pragma unroll
  for (int m = 0; m < 4; ++m) {
    const int u  = m * 512 + tid;
    const int c  = u >> 3;
    const int jb = u & 7;
    vs_g[m]   = c * NN + jb * 8;                 // + j0 at load time
    vs_off[m] = c * 128 + ((jb ^ (c & 7)) * 16); // swizzled LDS slot
  }

  floatx4 acc[8];
#pragma unroll
  for (int t = 0; t < 8; ++t) acc[t] = (floatx4){0.f, 0.f, 0.f, 0.f};
  float lsum[4] = {0.f, 0.f, 0.f, 0.f};

  // prologue: prefetch chunk 0 into registers (this wave's jt half only)
  intx4 vreg[4];
#pragma unroll
  for (int m = 0; m < 4; ++m)
    vreg[m] = *(const intx4*)(vb + vs_g[m]);
  short8 kf[2];
#pragma unroll
  for (int jt = 0; jt < 2; ++jt)
    kf[jt] = ld_frag_g(kTb + (size_t)((cs * 2 + jt) * 16 + lm) * CRD + lq * 8);

  const floatx4 zf = {0.f, 0.f, 0.f, 0.f};

#pragma unroll 1
  for (int k = 0; k < 64; ++k) {
    unsigned char* vbuf = smem + ((k & 1) << 15);
    unsigned char* pb   = smem + 65536 + (k & 1) * 8704 + wg * 2176;

    // phase 1a: stage prefetched V(k) into LDS parity k (race-free: barrier
    // A(k-1) guarantees all waves finished PV(k-2) reads of this buffer)
#pragma unroll
    for (int m = 0; m < 4; ++m)
      *(intx4*)(vbuf + vs_off[m]) = vreg[m];

    // phase 1b: this wave's half of S = Q K^T; clamp; exp; partial row sums
    floatx4 S[2];
#pragma unroll
    for (int jt = 0; jt < 2; ++jt) {
      S[jt] = __builtin_amdgcn_mfma_f32_16x16x32_bf16(qf, kf[jt], zf, 0, 0, 0);
#pragma unroll
      for (int r = 0; r < 4; ++r) {
        const float p = __expf(fminf(fmaxf(S[jt][r], -40.f), 40.f));
        S[jt][r] = p;
        lsum[r] += p;
      }
    }
#pragma unroll
    for (int jt = 0; jt < 2; ++jt)
#pragma unroll
      for (int r = 0; r < 4; ++r)
        *(unsigned short*)(pb + (lq * 4 + r) * 136 +
                           (((cs * 2 + jt) * 16 + lm) << 1)) = f2bf(S[jt][r]);

    // A: V(k) + full P(k) visible to all waves. LDS-only drain + raw
    // barrier -- global prefetches stay in flight (T4).
    asm volatile("s_waitcnt lgkmcnt(0)" ::: "memory");
    __builtin_amdgcn_s_barrier();

    // prefetch chunk k+1 into registers (consumed next iteration)
    if (k < 63) {
      const int j0n = (k + 1) << 6;
#pragma unroll
      for (int m = 0; m < 4; ++m)
        vreg[m] = *(const intx4*)(vb + vs_g[m] + j0n);
#pragma unroll
      for (int jt = 0; jt < 2; ++jt)
        kf[jt] = ld_frag_g(kTb +
                           (size_t)(j0n + (cs * 2 + jt) * 16 + lm) * CRD + lq * 8);
    }

    // phase 2: PV over this wave's 128-col c-half (reads parity k; iter k+1
    // writes hit parity k+1, so no trailing barrier needed)
#pragma unroll
    for (int ks = 0; ks < 2; ++ks) {
      const unsigned char* pa = pb + lm * 136 + ks * 64 + lq * 16;
      struct U128 { unsigned long long a, b; } pp;
      pp.a = *(const unsigned long long*)pa;
      pp.b = *(const unsigned long long*)(pa + 8);
      const short8 pf = __builtin_bit_cast(short8, pp);
#pragma unroll
      for (int nt = 0; nt < 8; ++nt) {
        const int c = cs * 128 + nt * 16 + lm;
        const short8 vf = __builtin_bit_cast(
            short8,
            *(const intx4*)(smem + ((k & 1) << 15) + c * 128 +
                            (((ks * 4 + lq) ^ (lm & 7)) * 16)));
        acc[nt] = __builtin_amdgcn_mfma_f32_16x16x32_bf16(pf, vf, acc[nt], 0, 0, 0);
      }
    }
    (void)vbuf;
  }

  // combine partial lsum across the cs wave pair (each saw half the j's)
  __syncthreads();
  floatx4 lv;
#pragma unroll
  for (int r = 0; r < 4; ++r) lv[r] = lsum[r];
  *(floatx4*)(smem + ((wave * 64 + lane) << 4)) = lv;
  __syncthreads();
  const floatx4 lpart = *(const floatx4*)(smem + (((wave ^ 1) * 64 + lane) << 4));

  float inv[4];
#pragma unroll
  for (int r = 0; r < 4; ++r) {
    float v = lsum[r] + lpart[r];
    v += __shfl_xor(v, 1);
    v += __shfl_xor(v, 2);
    v += __shfl_xor(v, 4);
    v += __shfl_xor(v, 8);
    inv[r] = 1.0f / v;
  }

  const float gm = gamma_p[0];
#pragma unroll
  for (int nt = 0; nt < 8; ++nt) {
#pragma unroll
    for (int r = 0; r < 4; ++r) {
      const int c = cs * 128 + nt * 16 + lm;
      const int i = i0 + wg * 16 + lq * 4 + r;
      const size_t idx = (size_t)(b * CCH + c) * NN + i;
      out[idx] = gm * sat(acc[nt][r] * inv[r]) + x[idx];
    }
  }
}

extern "C" void kernel_launch(void* const* d_in, const int* in_sizes, int n_in,
                              void* d_out, int out_size, void* d_ws, size_t ws_size,
                              hipStream_t stream) {
  (void)in_sizes; (void)n_in; (void)out_size; (void)ws_size;
  const float* x     = (const float*)d_in[0];
  const float* Wq    = (const float*)d_in[1];
  const float* bq    = (const float*)d_in[2];
  const float* Wk    = (const float*)d_in[3];
  const float* bk    = (const float*)d_in[4];
  const float* Wv    = (const float*)d_in[5];
  const float* bv    = (const float*)d_in[6];
  const float* gamma = (const float*)d_in[7];

  unsigned short* qT = (unsigned short*)d_ws;              // 1 MiB
  unsigned short* kT = qT + (size_t)NB * NN * CRD;         // 1 MiB
  unsigned short* vv = kT + (size_t)NB * NN * CRD;         // 8 MiB

  gemm_qkv_fused<<<dim3(64, 2, 4), 256, 0, stream>>>(x, Wq, bq, Wk, bk, Wv, bv,
                                                     qT, kT, vv);
  attn_kernel<<<dim3(256, 1, 1), 512, 0, stream>>>(x, gamma, qT, kT, vv,
                                                   (float*)d_out);
}

// Round 9
// 159.563 us; speedup vs baseline: 6.5190x; 1.0420x over previous
//
#include <hip/hip_runtime.h>
#include <hip/hip_bf16.h>

#define NB 4
#define CCH 256
#define CRD 32
#define NN 4096

typedef __attribute__((ext_vector_type(8))) short short8;
typedef __attribute__((ext_vector_type(4))) float floatx4;
typedef __attribute__((ext_vector_type(4))) int intx4;
typedef __attribute__((ext_vector_type(2))) unsigned int uintx2;

__device__ __forceinline__ unsigned short f2bf(float f) {
  unsigned u = __builtin_bit_cast(unsigned, f);
  u += 0x7FFFu + ((u >> 16) & 1u);
  return (unsigned short)(u >> 16);
}

// Clamped convert: finite bf16 regardless of input (NaN -> -1e4 via IEEE
// maxNum/minNum, +-inf -> +-1e4). Legit qkv values |v| < ~20: transparent.
__device__ __forceinline__ unsigned short f2bf_c(float f) {
  f = fminf(fmaxf(f, -1.0e4f), 1.0e4f);
  unsigned u = __builtin_bit_cast(unsigned, f);
  u += 0x7FFFu + ((u >> 16) & 1u);
  return (unsigned short)(u >> 16);
}

__device__ __forceinline__ unsigned pack2c(float a, float b) {
  return (unsigned)f2bf_c(a) | ((unsigned)f2bf_c(b) << 16);
}

// Output sanitizer: NaN -> -1e30 (IEEE maxNum), +-inf -> +-1e30.
__device__ __forceinline__ float sat(float v) {
  return fminf(fmaxf(v, -1.0e30f), 1.0e30f);
}

__device__ __forceinline__ short8 ld_frag_g(const unsigned short* p) {
  return __builtin_bit_cast(short8, *(const intx4*)p);
}

// ---------------------------------------------------------------------------
// Kernel 1: fused transpose + QKV GEMM (unchanged; stable since round 3).
// ---------------------------------------------------------------------------
__global__ __launch_bounds__(256) void gemm_qkv_fused(
    const float* __restrict__ x,
    const float* __restrict__ Wq, const float* __restrict__ bq,
    const float* __restrict__ Wk, const float* __restrict__ bk,
    const float* __restrict__ Wv, const float* __restrict__ bv,
    unsigned short* __restrict__ qT, unsigned short* __restrict__ kT,
    unsigned short* __restrict__ vv)
{
  __shared__ __align__(16) unsigned short xs[64 * 264];
  __shared__ __align__(16) unsigned short ws[64 * 264];

  const int tid  = threadIdx.x;
  const int wave = tid >> 6;
  const int lane = tid & 63;
  const int lq   = lane >> 4;
  const int lm   = lane & 15;
  const int n0   = blockIdx.x << 6;
  const int mg   = blockIdx.y;
  const int b    = blockIdx.z;

  {
    const int nn = lane;
    const int cg = wave;
    const float* xb = x + ((size_t)b << 20) + n0 + nn;
#pragma unroll
    for (int it = 0; it < 16; ++it) {
      const int c0 = it * 16 + cg * 4;
      const float v0 = xb[(size_t)(c0 + 0) << 12];
      const float v1 = xb[(size_t)(c0 + 1) << 12];
      const float v2 = xb[(size_t)(c0 + 2) << 12];
      const float v3 = xb[(size_t)(c0 + 3) << 12];
      uintx2 u;
      u[0] = pack2c(v0, v1);
      u[1] = pack2c(v2, v3);
      *(uintx2*)(xs + nn * 264 + c0) = u;
    }
  }

  const int mt_lo = mg ? 3 : 0;
  const int mt_hi = mg ? 5 : 3;

  for (int mt = mt_lo; mt < mt_hi; ++mt) {
#pragma unroll
    for (int i = 0; i < 16; ++i) {
      const int u  = i * 256 + tid;
      const int m  = u >> 6;
      const int o4 = (u & 63) * 4;
      const float* src = (mt == 0)
          ? (m < 32 ? Wq + (size_t)m * CCH : Wk + (size_t)(m - 32) * CCH)
          : Wv + (size_t)((mt - 1) * 64 + m) * CCH;
      const floatx4 f = *(const floatx4*)(src + o4);
      uintx2 uu;
      uu[0] = pack2c(f[0], f[1]);
      uu[1] = pack2c(f[2], f[3]);
      *(uintx2*)(ws + m * 264 + o4) = uu;
    }
    __syncthreads();

    floatx4 acc[4];
#pragma unroll
    for (int t = 0; t < 4; ++t) acc[t] = (floatx4){0.f, 0.f, 0.f, 0.f};

#pragma unroll
    for (int k0 = 0; k0 < 8; ++k0) {
      short8 af[4];
#pragma unroll
      for (int ms = 0; ms < 4; ++ms)
        af[ms] = __builtin_bit_cast(short8,
            *(const intx4*)(ws + (ms * 16 + lm) * 264 + k0 * 32 + lq * 8));
      const short8 bf = __builtin_bit_cast(short8,
          *(const intx4*)(xs + (wave * 16 + lm) * 264 + k0 * 32 + lq * 8));
#pragma unroll
      for (int ms = 0; ms < 4; ++ms)
        acc[ms] = __builtin_amdgcn_mfma_f32_16x16x32_bf16(af[ms], bf,
                                                          acc[ms], 0, 0, 0);
    }
    __syncthreads();

    if (mt == 0) {
      const int n = n0 + wave * 16 + lm;
#pragma unroll
      for (int ms = 0; ms < 4; ++ms) {
        const int d0 = (ms & 1) * 16 + lq * 4;
        const float* bias = (ms < 2) ? bq : bk;
        unsigned short* dst = (ms < 2) ? qT : kT;
        uintx2 u;
        u[0] = pack2c(acc[ms][0] + bias[d0],     acc[ms][1] + bias[d0 + 1]);
        u[1] = pack2c(acc[ms][2] + bias[d0 + 2], acc[ms][3] + bias[d0 + 3]);
        *(uintx2*)(dst + (size_t)(b * NN + n) * CRD + d0) = u;
      }
    } else {
      const int cb = (mt - 1) * 64;
      unsigned short* vb2 = ws;
#pragma unroll
      for (int ms = 0; ms < 4; ++ms)
#pragma unroll
        for (int r = 0; r < 4; ++r) {
          const int c = ms * 16 + lq * 4 + r;
          vb2[c * 64 + wave * 16 + lm] = f2bf_c(acc[ms][r] + bv[cb + c]);
        }
      __syncthreads();
#pragma unroll
      for (int it = 0; it < 2; ++it) {
        const int u = it * 256 + tid;
        const int m = u >> 3;
        const int o = (u & 7) * 8;
        *(intx4*)(vv + (size_t)(b * CCH + cb + m) * NN + n0 + o) =
            *(const intx4*)(vb2 + m * 64 + o);
      }
      __syncthreads();
    }
  }
}

// ---------------------------------------------------------------------------
// Kernel 2: attention = the 79.7 us r8 baseline (4wg x 2cs, V+P double-
// buffered, lgkm-only barrier) with ONE structural delta:
//   P SOFTWARE-PIPELINED BY ONE WINDOW. Old body: stage -> QK(k) -> exp ->
//   P-store -> [barrier] -> PV(k): exp+store on the pre-barrier critical
//   path, PV with nothing to overlap. New body (single straight-line block,
//   one barrier at top):
//     [lgkm barrier]            // V(k),P(k) written during iter k-1
//     stage V(k+1)              // ds_writes of prefetched vreg
//     QK(k+1)+exp+P-store(k+1)  // -> parity k+1
//     prefetch V(k+2),K(k+2)    // clamped index, branch-free
//     PV(k)                     // reads parity k; independent of all above
//   PV(k) and QK(k+1)+exp are data-independent in one basic block -> the
//   exp VALU chain hides under PV's 16 MFMAs. Race-free: writes at iter k
//   target parity (k+1); barrier at top of k guarantees PV(k-1) reads of
//   that parity completed (its lgkm drained before the previous barrier).
//   Loop peeled: k=0..62 full body; k=63 barrier+PV only.
// ---------------------------------------------------------------------------
__global__ __launch_bounds__(512) void attn_kernel(
    const float* __restrict__ x, const float* __restrict__ gamma_p,
    const unsigned short* __restrict__ qT, const unsigned short* __restrict__ kT,
    const unsigned short* __restrict__ vv, float* __restrict__ out)
{
  // [0,65536): V double buffer (2 x 256c x 64j bf16, swizzled)
  // [65536, +17408): P double buffer (2 parity x 4 wg x 16 i x 68col shorts)
  __shared__ __align__(16) unsigned char smem[65536 + 2 * 4 * 2176];

  const int tid  = threadIdx.x;
  const int wave = tid >> 6;
  const int wg   = wave >> 1;   // row-group 0..3 (16 rows each)
  const int cs   = wave & 1;    // c-slice / jt-half 0..1
  const int lane = tid & 63;
  const int lq   = lane >> 4;
  const int lm   = lane & 15;
  const int xcd = blockIdx.x & 7;
  const int pos = blockIdx.x >> 3;
  const int b   = xcd >> 1;
  const int i0  = (((xcd & 1) << 5) | pos) << 6;

  const unsigned short* kTb = kT + (size_t)b * NN * CRD;
  const unsigned short* vb  = vv + (size_t)b * CCH * NN;

  const short8 qf =
      ld_frag_g(qT + (size_t)(b * NN + i0 + wg * 16 + lm) * CRD + lq * 8);

  // per-lane V-stage coordinates: unit u = m*512+tid; c = u>>3; jb = u&7
  int vs_g[4];
  int vs_off[4];
#pragma unroll
  for (int m = 0; m < 4; ++m) {
    const int u  = m * 512 + tid;
    const int c  = u >> 3;
    const int jb = u & 7;
    vs_g[m]   = c * NN + jb * 8;                 // + j0 at load time
    vs_off[m] = c * 128 + ((jb ^ (c & 7)) * 16); // swizzled LDS slot
  }

  floatx4 acc[8];
#pragma unroll
  for (int t = 0; t < 8; ++t) acc[t] = (floatx4){0.f, 0.f, 0.f, 0.f};
  float lsum[4] = {0.f, 0.f, 0.f, 0.f};

  const floatx4 zf = {0.f, 0.f, 0.f, 0.f};

  // ---- prologue: build window 0 in parity 0, then prefetch window 1 ----
  intx4 vreg[4];
#pragma unroll
  for (int m = 0; m < 4; ++m)
    vreg[m] = *(const intx4*)(vb + vs_g[m]);
  short8 kf[2];
#pragma unroll
  for (int jt = 0; jt < 2; ++jt)
    kf[jt] = ld_frag_g(kTb + (size_t)((cs * 2 + jt) * 16 + lm) * CRD + lq * 8);

#pragma unroll
  for (int m = 0; m < 4; ++m)
    *(intx4*)(smem + vs_off[m]) = vreg[m];
  {
    unsigned char* pb0 = smem + 65536 + wg * 2176;
#pragma unroll
    for (int jt = 0; jt < 2; ++jt) {
      const floatx4 S = __builtin_amdgcn_mfma_f32_16x16x32_bf16(
          qf, kf[jt], zf, 0, 0, 0);
#pragma unroll
      for (int r = 0; r < 4; ++r) {
        const float p = __expf(fminf(fmaxf(S[r], -40.f), 40.f));
        lsum[r] += p;
        *(unsigned short*)(pb0 + (lq * 4 + r) * 136 +
                           (((cs * 2 + jt) * 16 + lm) << 1)) = f2bf(p);
      }
    }
  }
#pragma unroll
  for (int m = 0; m < 4; ++m)
    vreg[m] = *(const intx4*)(vb + vs_g[m] + 64);
#pragma unroll
  for (int jt = 0; jt < 2; ++jt)
    kf[jt] = ld_frag_g(kTb + (size_t)(64 + (cs * 2 + jt) * 16 + lm) * CRD +
                       lq * 8);

  // ---- main loop: k = 0..62, one barrier per iter, straight-line body ----
#pragma unroll 1
  for (int k = 0; k < 63; ++k) {
    // V(k),P(k) visible; PV(k-1) reads of parity (k+1)&1 complete.
    asm volatile("s_waitcnt lgkmcnt(0)" ::: "memory");
    __builtin_amdgcn_s_barrier();

    unsigned char* vbp = smem + ((k & 1) << 15);
    unsigned char* pbp = smem + 65536 + (k & 1) * 8704 + wg * 2176;
    unsigned char* vbn = smem + (((k + 1) & 1) << 15);
    unsigned char* pbn = smem + 65536 + ((k + 1) & 1) * 8704 + wg * 2176;

    // stage V(k+1) into parity k+1 (vreg prefetched last iter)
#pragma unroll
    for (int m = 0; m < 4; ++m)
      *(intx4*)(vbn + vs_off[m]) = vreg[m];

    // QK(k+1) + exp + P-store(k+1) -> parity k+1 (independent of PV(k))
#pragma unroll
    for (int jt = 0; jt < 2; ++jt) {
      const floatx4 S = __builtin_amdgcn_mfma_f32_16x16x32_bf16(
          qf, kf[jt], zf, 0, 0, 0);
#pragma unroll
      for (int r = 0; r < 4; ++r) {
        const float p = __expf(fminf(fmaxf(S[r], -40.f), 40.f));
        lsum[r] += p;
        *(unsigned short*)(pbn + (lq * 4 + r) * 136 +
                           (((cs * 2 + jt) * 16 + lm) << 1)) = f2bf(p);
      }
    }

    // prefetch window k+2 (clamped; redundant at k=62, branch-free body)
    {
      const int j2 = ((k + 2 < 64) ? (k + 2) : 63) << 6;
#pragma unroll
      for (int m = 0; m < 4; ++m)
        vreg[m] = *(const intx4*)(vb + vs_g[m] + j2);
#pragma unroll
      for (int jt = 0; jt < 2; ++jt)
        kf[jt] = ld_frag_g(kTb +
                           (size_t)(j2 + (cs * 2 + jt) * 16 + lm) * CRD + lq * 8);
    }

    // PV(k): this wave's 128-col c-half; reads V/P parity k
#pragma unroll
    for (int ks = 0; ks < 2; ++ks) {
      const unsigned char* pa = pbp + lm * 136 + ks * 64 + lq * 16;
      struct U128 { unsigned long long a, b; } pp;
      pp.a = *(const unsigned long long*)pa;
      pp.b = *(const unsigned long long*)(pa + 8);
      const short8 pf = __builtin_bit_cast(short8, pp);
#pragma unroll
      for (int nt = 0; nt < 8; ++nt) {
        const int c = cs * 128 + nt * 16 + lm;
        const short8 vf = __builtin_bit_cast(
            short8,
            *(const intx4*)(vbp + c * 128 + (((ks * 4 + lq) ^ (lm & 7)) * 16)));
        acc[nt] = __builtin_amdgcn_mfma_f32_16x16x32_bf16(pf, vf, acc[nt],
                                                          0, 0, 0);
      }
    }
  }

  // ---- epilogue iteration: PV(63), parity 1 ----
  asm volatile("s_waitcnt lgkmcnt(0)" ::: "memory");
  __builtin_amdgcn_s_barrier();
  {
    const unsigned char* vbp = smem + (1 << 15);
    const unsigned char* pbp = smem + 65536 + 8704 + wg * 2176;
#pragma unroll
    for (int ks = 0; ks < 2; ++ks) {
      const unsigned char* pa = pbp + lm * 136 + ks * 64 + lq * 16;
      struct U128 { unsigned long long a, b; } pp;
      pp.a = *(const unsigned long long*)pa;
      pp.b = *(const unsigned long long*)(pa + 8);
      const short8 pf = __builtin_bit_cast(short8, pp);
#pragma unroll
      for (int nt = 0; nt < 8; ++nt) {
        const int c = cs * 128 + nt * 16 + lm;
        const short8 vf = __builtin_bit_cast(
            short8,
            *(const intx4*)(vbp + c * 128 + (((ks * 4 + lq) ^ (lm & 7)) * 16)));
        acc[nt] = __builtin_amdgcn_mfma_f32_16x16x32_bf16(pf, vf, acc[nt],
                                                          0, 0, 0);
      }
    }
  }

  // combine partial lsum across the cs wave pair (each saw half the j's)
  __syncthreads();
  floatx4 lv;
#pragma unroll
  for (int r = 0; r < 4; ++r) lv[r] = lsum[r];
  *(floatx4*)(smem + ((wave * 64 + lane) << 4)) = lv;
  __syncthreads();
  const floatx4 lpart = *(const floatx4*)(smem + (((wave ^ 1) * 64 + lane) << 4));

  float inv[4];
#pragma unroll
  for (int r = 0; r < 4; ++r) {
    float v = lsum[r] + lpart[r];
    v += __shfl_xor(v, 1);
    v += __shfl_xor(v, 2);
    v += __shfl_xor(v, 4);
    v += __shfl_xor(v, 8);
    inv[r] = 1.0f / v;
  }

  const float gm = gamma_p[0];
#pragma unroll
  for (int nt = 0; nt < 8; ++nt) {
#pragma unroll
    for (int r = 0; r < 4; ++r) {
      const int c = cs * 128 + nt * 16 + lm;
      const int i = i0 + wg * 16 + lq * 4 + r;
      const size_t idx = (size_t)(b * CCH + c) * NN + i;
      out[idx] = gm * sat(acc[nt][r] * inv[r]) + x[idx];
    }
  }
}

extern "C" void kernel_launch(void* const* d_in, const int* in_sizes, int n_in,
                              void* d_out, int out_size, void* d_ws, size_t ws_size,
                              hipStream_t stream) {
  (void)in_sizes; (void)n_in; (void)out_size; (void)ws_size;
  const float* x     = (const float*)d_in[0];
  const float* Wq    = (const float*)d_in[1];
  const float* bq    = (const float*)d_in[2];
  const float* Wk    = (const float*)d_in[3];
  const float* bk    = (const float*)d_in[4];
  const float* Wv    = (const float*)d_in[5];
  const float* bv    = (const float*)d_in[6];
  const float* gamma = (const float*)d_in[7];

  unsigned short* qT = (unsigned short*)d_ws;              // 1 MiB
  unsigned short* kT = qT + (size_t)NB * NN * CRD;         // 1 MiB
  unsigned short* vv = kT + (size_t)NB * NN * CRD;         // 8 MiB

  gemm_qkv_fused<<<dim3(64, 2, 4), 256, 0, stream>>>(x, Wq, bq, Wk, bk, Wv, bv,
                                                     qT, kT, vv);
  attn_kernel<<<dim3(256, 1, 1), 512, 0, stream>>>(x, gamma, qT, kT, vv,
                                                   (float*)d_out);
}